// Round 5
// baseline (116.141 us; speedup 1.0000x reference)
//
#include <hip/hip_runtime.h>

// Problem constants (fixed by the reference setup)
#define NB 8
#define KF 16
#define HGT 256
#define WID 256
#define HW (HGT * WID)          // 65536
#define NPIX (NB * HW)          // 524288
#define NPTS 100000
#define NCH 4
#define KHALF 8                 // k-split: each thread owns 8 of the 16 layers

// ---------------------------------------------------------------------------
// Kernel 1: transpose ptclds (C,P) -> (P, 4) float4 so each gather is one
// 16B L2 transaction instead of four 4B ones. ptclds is 1.6 MB -> L2-resident.
// ---------------------------------------------------------------------------
__global__ void ptclds_transpose_kernel(const float* __restrict__ pt,
                                        float4* __restrict__ ws) {
    int p = blockIdx.x * blockDim.x + threadIdx.x;
    if (p < NPTS) {
        ws[p] = make_float4(pt[p],
                            pt[NPTS + p],
                            pt[2 * NPTS + p],
                            pt[3 * NPTS + p]);
    }
}

// ---------------------------------------------------------------------------
// Kernel 2: k-split compositing. Thread <-> (pixel, k-half).
//   acc_full = acc0 + T0 * acc1   where
//   acc_h = sum_{k in half} a_k prod_{j<k in half}(1-a_j) g_k,
//   T0    = prod_{k<8}(1-a_k).
// 1M threads (4096 blocks) -> full occupancy; per-thread chain halved vs R4;
// gather request count unchanged (the discriminating experiment).
// NO nontemporal builtins (R3 lesson: nt stores race the 0xAA poison fill).
// ---------------------------------------------------------------------------
template <bool PACKED>
__global__ __launch_bounds__(256, 6) void composite_split_kernel(
    const int* __restrict__ frags,     // (N,K,H,W)
    const float* __restrict__ alphas,  // (N,K,H,W)
    const float* __restrict__ pt,      // (C,P)  (used when !PACKED)
    const float4* __restrict__ ws,     // (P,4)  (used when PACKED)
    const float* __restrict__ bg,      // (3,)
    float* __restrict__ out)           // (N,C,H,W)
{
    // Block: 256 threads = 128 pixels x 2 k-halves.
    const int lpx  = threadIdx.x & 127;        // pixel slot within block
    const int half = threadIdx.x >> 7;         // 0: k=0..7, 1: k=8..15
    const int px   = (blockIdx.x << 7) | lpx;  // global pixel

    const int n  = px >> 16;          // px / HW
    const int hw = px & (HW - 1);     // px % HW

    long base = (long)n * KF * HW + (long)(half * KHALF) * HW + hw;

    // Stage this half's fragment indices and alphas: 16 independent loads.
    int f[KHALF];
    float a[KHALF];
    #pragma unroll
    for (int j = 0; j < KHALF; ++j)
        f[j] = frags[base + (long)j * HW];
    #pragma unroll
    for (int j = 0; j < KHALF; ++j)
        a[j] = alphas[base + (long)j * HW];

    float4 acc = make_float4(0.f, 0.f, 0.f, 0.f);
    float T = 1.0f;

    #pragma unroll
    for (int j = 0; j < KHALF; ++j) {
        const bool v = f[j] >= 0;
        const int idx = v ? f[j] : 0;   // invalid -> broadcast line 0
        float4 g;
        if (PACKED) {
            g = ws[idx];
        } else {
            g = make_float4(pt[idx], pt[NPTS + idx],
                            pt[2 * NPTS + idx], pt[3 * NPTS + idx]);
        }
        const float av = v ? a[j] : 0.f;
        const float w = av * T;
        acc.x += w * g.x;
        acc.y += w * g.y;
        acc.z += w * g.z;
        acc.w += w * g.w;
        T *= (1.0f - av);
    }

    // Combine halves: half-1 publishes acc1; half-0 folds and stores.
    __shared__ float4 s_acc[128];
    if (half == 1) s_acc[lpx] = acc;
    __syncthreads();

    if (half == 0) {
        const float4 acc1 = s_acc[lpx];
        float4 r = make_float4(acc.x + T * acc1.x,
                               acc.y + T * acc1.y,
                               acc.z + T * acc1.z,
                               acc.w + T * acc1.w);
        if (f[0] < 0) r = make_float4(bg[0], bg[1], bg[2], 1.0f);

        long ob = (long)n * NCH * HW + hw;
        out[ob]          = r.x;
        out[ob + HW]     = r.y;
        out[ob + 2 * HW] = r.z;
        out[ob + 3 * HW] = r.w;
    }
}

extern "C" void kernel_launch(void* const* d_in, const int* in_sizes, int n_in,
                              void* d_out, int out_size, void* d_ws, size_t ws_size,
                              hipStream_t stream) {
    const int*   frags  = (const int*)d_in[0];    // fragments (N,K,H,W) int32
    const float* alphas = (const float*)d_in[1];  // alphas    (N,K,H,W) f32
    const float* pt     = (const float*)d_in[2];  // ptclds    (C,P)     f32
    const float* bg     = (const float*)d_in[3];  // background_color (3,) f32
    float* out = (float*)d_out;                   // (N,C,H,W) f32

    const bool packed = (ws_size >= (size_t)NPTS * sizeof(float4));
    const int nblocks = (NPIX * 2) / 256;         // 4096

    if (packed) {
        float4* ws = (float4*)d_ws;
        ptclds_transpose_kernel<<<(NPTS + 255) / 256, 256, 0, stream>>>(pt, ws);
        composite_split_kernel<true><<<nblocks, 256, 0, stream>>>(
            frags, alphas, pt, ws, bg, out);
    } else {
        composite_split_kernel<false><<<nblocks, 256, 0, stream>>>(
            frags, alphas, pt, (const float4*)nullptr, bg, out);
    }
}

// Round 6
// 115.389 us; speedup vs baseline: 1.0065x; 1.0065x over previous
//
#include <hip/hip_runtime.h>
#include <hip/hip_fp16.h>

// Problem constants (fixed by the reference setup)
#define NB 8
#define KF 16
#define HGT 256
#define WID 256
#define HW (HGT * WID)          // 65536
#define NPIX (NB * HW)          // 524288
#define NPTS 100000
#define NCH 4

// ---------------------------------------------------------------------------
// Kernel 1: transpose + pack ptclds (C,P) f32 -> (P) 4xfp16 (8B per point).
// Features are uniform [0,1): fp16 error <= 2^-12/feature; weights sum <= 1,
// so added output error <= ~3e-4 (threshold is 2e-2). Halves the per-lane
// bytes returned by every random gather (TD return-path hypothesis).
// ---------------------------------------------------------------------------
__global__ void ptclds_pack_kernel(const float* __restrict__ pt,
                                   uint2* __restrict__ ws) {
    int p = blockIdx.x * blockDim.x + threadIdx.x;
    if (p < NPTS) {
        __half2 h01 = __floats2half2_rn(pt[p],            pt[NPTS + p]);
        __half2 h23 = __floats2half2_rn(pt[2 * NPTS + p], pt[3 * NPTS + p]);
        uint2 q;
        q.x = *reinterpret_cast<unsigned int*>(&h01);
        q.y = *reinterpret_cast<unsigned int*>(&h23);
        ws[p] = q;
    }
}

// ---------------------------------------------------------------------------
// Kernel 2: branchless compositing, 1 pixel per thread (2048 blocks).
// Identical structure to R4 (the 39us baseline) except gathers are 8B fp16x4.
// NO nontemporal builtins (R3 lesson: nt stores race the 0xAA poison fill).
// ---------------------------------------------------------------------------
template <bool PACKED>
__global__ __launch_bounds__(256, 6) void composite_kernel(
    const int* __restrict__ frags,     // (N,K,H,W)
    const float* __restrict__ alphas,  // (N,K,H,W)
    const float* __restrict__ pt,      // (C,P)  (used when !PACKED)
    const uint2* __restrict__ ws,      // (P) 4xfp16 (used when PACKED)
    const float* __restrict__ bg,      // (3,)
    float* __restrict__ out)           // (N,C,H,W)
{
    int i = blockIdx.x * blockDim.x + threadIdx.x;
    if (i >= NPIX) return;

    int n  = i >> 16;          // i / HW
    int hw = i & (HW - 1);     // i % HW

    long base = (long)n * KF * HW + hw;

    // Stage all fragment indices and alphas: 32 independent coalesced loads.
    int f[KF];
    float a[KF];
    #pragma unroll
    for (int k = 0; k < KF; ++k)
        f[k] = frags[base + (long)k * HW];
    #pragma unroll
    for (int k = 0; k < KF; ++k)
        a[k] = alphas[base + (long)k * HW];

    float4 acc = make_float4(0.f, 0.f, 0.f, 0.f);
    float T = 1.0f;

    #pragma unroll
    for (int k = 0; k < KF; ++k) {
        const bool v = f[k] >= 0;
        const int idx = v ? f[k] : 0;   // invalid -> broadcast line 0
        float4 g;
        if (PACKED) {
            const uint2 q = ws[idx];
            const __half2 h01 = *reinterpret_cast<const __half2*>(&q.x);
            const __half2 h23 = *reinterpret_cast<const __half2*>(&q.y);
            const float2 g01 = __half22float2(h01);
            const float2 g23 = __half22float2(h23);
            g = make_float4(g01.x, g01.y, g23.x, g23.y);
        } else {
            g = make_float4(pt[idx], pt[NPTS + idx],
                            pt[2 * NPTS + idx], pt[3 * NPTS + idx]);
        }
        const float av = v ? a[k] : 0.f;
        const float w = av * T;
        acc.x += w * g.x;
        acc.y += w * g.y;
        acc.z += w * g.z;
        acc.w += w * g.w;
        T *= (1.0f - av);
    }

    // Background fill where no nearest point exists.
    if (f[0] < 0) acc = make_float4(bg[0], bg[1], bg[2], 1.0f);

    long ob = (long)n * NCH * HW + hw;
    out[ob]          = acc.x;
    out[ob + HW]     = acc.y;
    out[ob + 2 * HW] = acc.z;
    out[ob + 3 * HW] = acc.w;
}

extern "C" void kernel_launch(void* const* d_in, const int* in_sizes, int n_in,
                              void* d_out, int out_size, void* d_ws, size_t ws_size,
                              hipStream_t stream) {
    const int*   frags  = (const int*)d_in[0];    // fragments (N,K,H,W) int32
    const float* alphas = (const float*)d_in[1];  // alphas    (N,K,H,W) f32
    const float* pt     = (const float*)d_in[2];  // ptclds    (C,P)     f32
    const float* bg     = (const float*)d_in[3];  // background_color (3,) f32
    float* out = (float*)d_out;                   // (N,C,H,W) f32

    const bool packed = (ws_size >= (size_t)NPTS * sizeof(uint2));

    if (packed) {
        uint2* ws = (uint2*)d_ws;
        ptclds_pack_kernel<<<(NPTS + 255) / 256, 256, 0, stream>>>(pt, ws);
        composite_kernel<true><<<NPIX / 256, 256, 0, stream>>>(
            frags, alphas, pt, ws, bg, out);
    } else {
        composite_kernel<false><<<NPIX / 256, 256, 0, stream>>>(
            frags, alphas, pt, (const uint2*)nullptr, bg, out);
    }
}